// Round 1
// 1028.358 us; speedup vs baseline: 1.1295x; 1.1295x over previous
//
#include <hip/hip_runtime.h>

#define NPIX 262144
#define NCLS 19
#define DF 256
#define REPL 16

// workspace layout (float indices)
#define OFF_SUM  0                       // REPL * 4864, permuted layout sigma(d)*19+c
#define OFF_DEN  77824                   // REPL * 19
#define OFF_WSUM 78128                   // REPL
#define OFF_TOT  78144                   // REPL
#define OFF_SEEN 78160                   // 1 (int bitmask)
#define OFF_CENT 78176                   // 4864, row-major c*256+d (cent_safe)
#define MEMSET_BYTES (OFF_CENT * 4)

// -------------------- phase 1: per-class weighted sums --------------------
// 2048 blocks (8/CU, LDS-limited exactly), 256 rows per block.
// Each wave preloads its 64 row descriptors (class, weight) with ONE coalesced
// load per array, then broadcasts per-row via __shfl -> no per-iteration global
// latency on the index path. Feature loads unrolled x2 for in-flight overlap.
__global__ __launch_bounds__(256) void k_phase1(
    const float* __restrict__ sfeat, const float* __restrict__ tfeat,
    const float* __restrict__ conf, const int* __restrict__ sarg,
    const int* __restrict__ targ, const int* __restrict__ smask,
    float* __restrict__ ws)
{
    __shared__ float lsum[NCLS * DF];
    __shared__ float lden[NCLS];
    const int t = threadIdx.x;
    for (int j = t; j < NCLS * DF; j += 256) lsum[j] = 0.f;
    if (t < NCLS) lden[t] = 0.f;
    __syncthreads();

    const int lane = t & 63;
    const int wv = t >> 6;
    const int gBase = blockIdx.x * 256 + wv * 64;   // this wave's 64 interleaved rows
    const int iBase = gBase >> 1;

    // one row descriptor per lane: even lanes = source row, odd lanes = target row
    const int il = iBase + (lane >> 1);
    int cl; float wtl;
    if (lane & 1) { cl = targ[il]; wtl = 1.f - conf[il]; }
    else          { cl = sarg[il]; wtl = smask[il] ? 1.f : 0.f; }
    float wloc = (lane & 1) ? 0.f : wtl;            // source-mask weight sum (per lane)

    for (int it = 0; it < 64; it += 2) {
        // it even -> row g0=gBase+it is source (lane it), g1 is target (lane it+1)
        const int   c0 = __shfl(cl,  it);
        const float w0 = __shfl(wtl, it);
        const int   c1 = __shfl(cl,  it + 1);
        const float w1 = __shfl(wtl, it + 1);
        const size_t i = (size_t)iBase + (it >> 1);
        const bool v0 = (w0 != 0.f);
        const bool v1 = (w1 != 0.f);
        float4 f0, f1;
        if (v0) f0 = ((const float4*)(sfeat + i * DF))[lane];
        if (v1) f1 = ((const float4*)(tfeat + i * DF))[lane];
        if (v0) {
            // dims d = 4*lane+k -> lds addr (k*64+lane)*19+c : conflict-free
            unsafeAtomicAdd(&lsum[(0 * 64 + lane) * NCLS + c0], w0 * f0.x);
            unsafeAtomicAdd(&lsum[(1 * 64 + lane) * NCLS + c0], w0 * f0.y);
            unsafeAtomicAdd(&lsum[(2 * 64 + lane) * NCLS + c0], w0 * f0.z);
            unsafeAtomicAdd(&lsum[(3 * 64 + lane) * NCLS + c0], w0 * f0.w);
            if (lane == 0) unsafeAtomicAdd(&lden[c0], w0);
        }
        if (v1) {
            unsafeAtomicAdd(&lsum[(0 * 64 + lane) * NCLS + c1], w1 * f1.x);
            unsafeAtomicAdd(&lsum[(1 * 64 + lane) * NCLS + c1], w1 * f1.y);
            unsafeAtomicAdd(&lsum[(2 * 64 + lane) * NCLS + c1], w1 * f1.z);
            unsafeAtomicAdd(&lsum[(3 * 64 + lane) * NCLS + c1], w1 * f1.w);
            if (lane == 0) unsafeAtomicAdd(&lden[c1], w1);
        }
    }

    // wave-reduce source-weight sum, one atomic per wave
    wloc += __shfl_xor(wloc, 32); wloc += __shfl_xor(wloc, 16);
    wloc += __shfl_xor(wloc, 8);  wloc += __shfl_xor(wloc, 4);
    wloc += __shfl_xor(wloc, 2);  wloc += __shfl_xor(wloc, 1);
    const int rep = blockIdx.x & (REPL - 1);
    if (lane == 0) unsafeAtomicAdd(&ws[OFF_WSUM + rep], wloc);
    __syncthreads();

    float* gsum = ws + OFF_SUM + rep * (NCLS * DF);
    for (int j = t; j < NCLS * DF; j += 256) {
        const float v = lsum[j];
        if (v != 0.f) unsafeAtomicAdd(&gsum[j], v);
    }
    if (t < NCLS) unsafeAtomicAdd(&ws[OFF_DEN + rep * NCLS + t], lden[t]);
}

// -------------------- finalize centroids --------------------
__global__ __launch_bounds__(256) void k_centroids(float* __restrict__ ws,
                                                   float* __restrict__ out)
{
    const int c = blockIdx.x;      // 19 blocks
    const int d = threadIdx.x;     // 256 dims
    float den = 0.f;
    for (int r = 0; r < REPL; ++r) den += ws[OFF_DEN + r * NCLS + c];
    const bool seen = den > 0.f;
    const int sig = (d & 3) * 64 + (d >> 2);   // same permutation as phase 1
    float s = 0.f;
    for (int r = 0; r < REPL; ++r) s += ws[OFF_SUM + r * (NCLS * DF) + sig * NCLS + c];
    const float centv = seen ? s / fmaxf(den, 1e-12f) : __builtin_inff();
    out[c * DF + d] = centv;                       // reference: inf for unseen
    ws[OFF_CENT + c * DF + d] = seen ? centv : 0.f; // cent_safe for phase 2
    if (d == 0 && seen) atomicOr((int*)ws + OFF_SEEN, 1 << c);
}

// -------------------- phase 2: similarity entropy --------------------
// 4 lanes per pixel, 4 pixels per lane-group: each LDS centroid float4 read
// feeds 16 FMAs (4 px * dot4) -> 4x less LDS traffic. Fused 3-shuffle
// transpose-reduce leaves lane sub holding its own pixel's 19 logits, so the
// softmax-entropy epilogue runs once per pixel (not 16x redundant).
__global__ __launch_bounds__(256) void k_entropy(
    const float* __restrict__ sfeat, const float* __restrict__ tfeat,
    const float* __restrict__ conf, const int* __restrict__ smask,
    float* __restrict__ ws)
{
    __shared__ float cent[NCLS * DF];
    __shared__ int seenSh;
    __shared__ float wacc[4];
    const int t = threadIdx.x;
    for (int j = t; j < NCLS * DF; j += 256) cent[j] = ws[OFF_CENT + j];
    if (t == 0) seenSh = ((const int*)ws)[OFF_SEEN];
    __syncthreads();
    const int seenM = seenSh;

    const int lane = t & 63, wv = t >> 6;
    const int sub = lane & 3, grp = lane >> 2;             // 16 groups of 4 lanes
    const int iBase = blockIdx.x * 128 + wv * 32 + grp * 2; // this group's 2 pixel-pairs

    // group pixel weights (broadcast loads, identical across the 4 lanes)
    const float w0 = smask[iBase]     ? 1.f : 0.f;          // source px iBase
    const float w1 = 1.f - conf[iBase];                     // target px iBase
    const float w2 = smask[iBase + 1] ? 1.f : 0.f;          // source px iBase+1
    const float w3 = 1.f - conf[iBase + 1];                 // target px iBase+1

    const float4* r0 = (const float4*)(sfeat + (size_t)iBase * DF);
    const float4* r1 = (const float4*)(tfeat + (size_t)iBase * DF);
    const float4* r2 = (const float4*)(sfeat + (size_t)(iBase + 1) * DF);
    const float4* r3 = (const float4*)(tfeat + (size_t)(iBase + 1) * DF);
    const float4* cv = (const float4*)cent;

    float z0[NCLS], z1[NCLS], z2[NCLS], z3[NCLS];
    #pragma unroll
    for (int c = 0; c < NCLS; ++c) { z0[c]=0.f; z1[c]=0.f; z2[c]=0.f; z3[c]=0.f; }

    const float4 zero4 = make_float4(0.f, 0.f, 0.f, 0.f);
    #pragma unroll 2
    for (int q = 0; q < 16; ++q) {
        const int o = sub + 4 * q;                  // lane's float4 slot in the row
        float4 f0 = (w0 != 0.f) ? r0[o] : zero4;    // skip masked source reads
        float4 f1 = r1[o];
        float4 f2 = (w2 != 0.f) ? r2[o] : zero4;
        float4 f3 = r3[o];
        #pragma unroll
        for (int c = 0; c < NCLS; ++c) {
            const float4 cc = cv[c * 64 + o];       // 16-way broadcast across groups
            z0[c] += f0.x*cc.x + f0.y*cc.y + f0.z*cc.z + f0.w*cc.w;
            z1[c] += f1.x*cc.x + f1.y*cc.y + f1.z*cc.z + f1.w*cc.w;
            z2[c] += f2.x*cc.x + f2.y*cc.y + f2.z*cc.z + f2.w*cc.w;
            z3[c] += f3.x*cc.x + f3.y*cc.y + f3.z*cc.z + f3.w*cc.w;
        }
    }

    // fused transpose-reduce across the 4-lane group: 3 shuffles per class,
    // lane sub ends holding the full logit for pixel (iBase-group, index sub)
    const bool s1b = (sub & 1) != 0;
    const bool s2b = (sub & 2) != 0;
    float zm[NCLS];
    #pragma unroll
    for (int c = 0; c < NCLS; ++c) {
        float a  = s1b ? z1[c] : z0[c];
        float b  = s1b ? z0[c] : z1[c];
        a += __shfl_xor(b, 1);                      // px (sub&1) over lane-pair dims
        float a2 = s1b ? z3[c] : z2[c];
        float b2 = s1b ? z2[c] : z3[c];
        a2 += __shfl_xor(b2, 1);                    // px 2|(sub&1) over lane-pair dims
        float k  = s2b ? a2 : a;
        float s  = s2b ? a  : a2;
        zm[c] = k + __shfl_xor(s, 2);               // px sub over all 4 lanes
    }

    // masked log-softmax entropy for this lane's own pixel
    const float wme = s1b ? (s2b ? w3 : w1) : (s2b ? w2 : w0);
    float m = -3.4e38f;
    #pragma unroll
    for (int c = 0; c < NCLS; ++c)
        if ((seenM >> c) & 1) m = fmaxf(m, zm[c]);
    float ssum = 0.f, t1 = 0.f;
    #pragma unroll
    for (int c = 0; c < NCLS; ++c)
        if ((seenM >> c) & 1) {
            const float e = __expf(zm[c] - m);
            ssum += e; t1 += e * (zm[c] - m);
        }
    const float ent = t1 / ssum - __logf(ssum);
    float acc = (wme != 0.f) ? wme * ent : 0.f;

    // wave + block reduction of weighted entropy sum
    acc += __shfl_xor(acc, 32); acc += __shfl_xor(acc, 16);
    acc += __shfl_xor(acc, 8);  acc += __shfl_xor(acc, 4);
    acc += __shfl_xor(acc, 2);  acc += __shfl_xor(acc, 1);
    if (lane == 0) wacc[wv] = acc;
    __syncthreads();
    if (t == 0)
        unsafeAtomicAdd(&ws[OFF_TOT + (blockIdx.x & (REPL - 1))],
                        wacc[0] + wacc[1] + wacc[2] + wacc[3]);
}

// -------------------- finalize loss --------------------
__global__ void k_loss(const float* __restrict__ ws, float* __restrict__ out)
{
    if (threadIdx.x == 0 && blockIdx.x == 0) {
        float tot = 0.f, wsum = 0.f;
        for (int r = 0; r < REPL; ++r) { tot += ws[OFF_TOT + r]; wsum += ws[OFF_WSUM + r]; }
        out[NCLS * DF] = -tot / (wsum + (float)NPIX);
    }
}

extern "C" void kernel_launch(void* const* d_in, const int* in_sizes, int n_in,
                              void* d_out, int out_size, void* d_ws, size_t ws_size,
                              hipStream_t stream)
{
    const float* sfeat = (const float*)d_in[0];
    const float* tfeat = (const float*)d_in[1];
    const float* conf  = (const float*)d_in[2];
    const int*   sarg  = (const int*)d_in[3];
    const int*   targ  = (const int*)d_in[4];
    const int*   smask = (const int*)d_in[5];
    float* out = (float*)d_out;
    float* ws  = (float*)d_ws;

    hipMemsetAsync(d_ws, 0, MEMSET_BYTES, stream);
    k_phase1   <<<2048, 256, 0, stream>>>(sfeat, tfeat, conf, sarg, targ, smask, ws);
    k_centroids<<<NCLS, 256, 0, stream>>>(ws, out);
    k_entropy  <<<2048, 256, 0, stream>>>(sfeat, tfeat, conf, smask, ws);
    k_loss     <<<1,    64,  0, stream>>>(ws, out);
}

// Round 2
// 726.255 us; speedup vs baseline: 1.5993x; 1.4160x over previous
//
#include <hip/hip_runtime.h>

#define NPIX 262144
#define NCLS 19
#define DF 256
#define REPL 16

// workspace layout (float indices)
#define OFF_SUM  0                       // REPL * 4864, row-major c*256+d
#define OFF_DEN  77824                   // REPL * 19
#define OFF_WSUM 78128                   // REPL
#define OFF_TOT  78144                   // REPL
#define OFF_SEEN 78160                   // 1 (int bitmask)
#define OFF_CENT 78176                   // 4864, row-major c*256+d (cent_safe)
#define MEMSET_BYTES (OFF_CENT * 4)

// -------------------- phase 1: per-class weighted sums --------------------
// Register accumulation: 19 classes x float4 per lane (76 VGPR), branchless
// compare-select weights, unconditional pipelined float4 loads. ZERO LDS
// atomics in the inner loop (prev rounds: ~100M lane-level ds_add RMWs --
// the serialized resource that made duration insensitive to occupancy).
__global__ __launch_bounds__(256) void k_phase1(
    const float* __restrict__ sfeat, const float* __restrict__ tfeat,
    const float* __restrict__ conf, const int* __restrict__ sarg,
    const int* __restrict__ targ, const int* __restrict__ smask,
    float* __restrict__ ws)
{
    __shared__ float buf0[NCLS * DF];
    __shared__ float buf1[NCLS * DF];
    __shared__ float lden[NCLS];
    const int t = threadIdx.x;
    if (t < NCLS) lden[t] = 0.f;
    __syncthreads();

    const int lane = t & 63;
    const int wv = t >> 6;
    const int iBase = blockIdx.x * 128 + wv * 32;   // 32 pixel-pairs (64 rows) per wave

    // descriptors: lane 2j -> source row iBase+j, lane 2j+1 -> target row iBase+j
    const int il = iBase + (lane >> 1);
    int cl; float wtl;
    if (lane & 1) { cl = targ[il]; wtl = 1.f - conf[il]; }
    else          { cl = sarg[il]; wtl = smask[il] ? 1.f : 0.f; }
    atomicAdd(&lden[cl], wtl);                      // ONE ds atomic per row total
    float wloc = (lane & 1) ? 0.f : wtl;            // source-weight partial

    float acc[NCLS][4];
    #pragma unroll
    for (int c = 0; c < NCLS; ++c)
        acc[c][0] = acc[c][1] = acc[c][2] = acc[c][3] = 0.f;

    const float4* sf = (const float4*)(sfeat + (size_t)iBase * DF);
    const float4* tf = (const float4*)(tfeat + (size_t)iBase * DF);

    #pragma unroll 4
    for (int it = 0; it < 32; ++it) {
        const int   c0 = __shfl(cl,  2 * it);
        const float w0 = __shfl(wtl, 2 * it);
        const int   c1 = __shfl(cl,  2 * it + 1);
        const float w1 = __shfl(wtl, 2 * it + 1);
        const float4 f0 = sf[it * 64 + lane];       // unconditional: pipelineable
        const float4 f1 = tf[it * 64 + lane];
        #pragma unroll
        for (int c = 0; c < NCLS; ++c) {
            const float ws0 = (c0 == c) ? w0 : 0.f;
            const float ws1 = (c1 == c) ? w1 : 0.f;
            acc[c][0] += ws0 * f0.x + ws1 * f1.x;
            acc[c][1] += ws0 * f0.y + ws1 * f1.y;
            acc[c][2] += ws0 * f0.z + ws1 * f1.z;
            acc[c][3] += ws0 * f0.w + ws1 * f1.w;
        }
    }

    // cross-wave combine, atomic-free: waves 0,1 write own buffer; waves 2,3 add
    float4* b = (float4*)((wv & 1) ? buf1 : buf0);
    if (wv < 2) {
        #pragma unroll
        for (int c = 0; c < NCLS; ++c)
            b[c * 64 + lane] = make_float4(acc[c][0], acc[c][1], acc[c][2], acc[c][3]);
    }
    __syncthreads();
    if (wv >= 2) {
        #pragma unroll
        for (int c = 0; c < NCLS; ++c) {
            float4 v = b[c * 64 + lane];
            v.x += acc[c][0]; v.y += acc[c][1]; v.z += acc[c][2]; v.w += acc[c][3];
            b[c * 64 + lane] = v;
        }
    }

    // per-wave source-weight reduce, one global atomic per wave
    wloc += __shfl_xor(wloc, 32); wloc += __shfl_xor(wloc, 16);
    wloc += __shfl_xor(wloc, 8);  wloc += __shfl_xor(wloc, 4);
    wloc += __shfl_xor(wloc, 2);  wloc += __shfl_xor(wloc, 1);
    const int rep = blockIdx.x & (REPL - 1);
    if (lane == 0) unsafeAtomicAdd(&ws[OFF_WSUM + rep], wloc);
    __syncthreads();

    float* gsum = ws + OFF_SUM + rep * (NCLS * DF);
    for (int j = t; j < NCLS * DF; j += 256) {
        const float v = buf0[j] + buf1[j];
        if (v != 0.f) unsafeAtomicAdd(&gsum[j], v);
    }
    if (t < NCLS) unsafeAtomicAdd(&ws[OFF_DEN + rep * NCLS + t], lden[t]);
}

// -------------------- finalize centroids --------------------
__global__ __launch_bounds__(256) void k_centroids(float* __restrict__ ws,
                                                   float* __restrict__ out)
{
    const int c = blockIdx.x;      // 19 blocks
    const int d = threadIdx.x;     // 256 dims
    float den = 0.f;
    for (int r = 0; r < REPL; ++r) den += ws[OFF_DEN + r * NCLS + c];
    const bool seen = den > 0.f;
    float s = 0.f;
    for (int r = 0; r < REPL; ++r) s += ws[OFF_SUM + r * (NCLS * DF) + c * DF + d];
    const float centv = seen ? s / fmaxf(den, 1e-12f) : __builtin_inff();
    out[c * DF + d] = centv;                       // reference: inf for unseen
    ws[OFF_CENT + c * DF + d] = seen ? centv : 0.f; // cent_safe for phase 2
    if (d == 0 && seen) atomicOr((int*)ws + OFF_SEEN, 1 << c);
}

// -------------------- phase 2: similarity entropy --------------------
// 4 lanes per pixel, 4 pixels per lane-group. Loads are now UNCONDITIONAL
// (masked pixels' logits are finite and multiplied by wme==0 at the end):
// removes the divergent branch around loads that blocked software pipelining.
__global__ __launch_bounds__(256) void k_entropy(
    const float* __restrict__ sfeat, const float* __restrict__ tfeat,
    const float* __restrict__ conf, const int* __restrict__ smask,
    float* __restrict__ ws)
{
    __shared__ float cent[NCLS * DF];
    __shared__ int seenSh;
    __shared__ float wacc[4];
    const int t = threadIdx.x;
    for (int j = t; j < NCLS * DF; j += 256) cent[j] = ws[OFF_CENT + j];
    if (t == 0) seenSh = ((const int*)ws)[OFF_SEEN];
    __syncthreads();
    const int seenM = seenSh;

    const int lane = t & 63, wv = t >> 6;
    const int sub = lane & 3, grp = lane >> 2;              // 16 groups of 4 lanes
    const int iBase = blockIdx.x * 128 + wv * 32 + grp * 2; // 2 pixel-pairs per group

    const float w0 = smask[iBase]     ? 1.f : 0.f;          // source px iBase
    const float w1 = 1.f - conf[iBase];                     // target px iBase
    const float w2 = smask[iBase + 1] ? 1.f : 0.f;          // source px iBase+1
    const float w3 = 1.f - conf[iBase + 1];                 // target px iBase+1

    const float4* r0 = (const float4*)(sfeat + (size_t)iBase * DF);
    const float4* r1 = (const float4*)(tfeat + (size_t)iBase * DF);
    const float4* r2 = (const float4*)(sfeat + (size_t)(iBase + 1) * DF);
    const float4* r3 = (const float4*)(tfeat + (size_t)(iBase + 1) * DF);
    const float4* cv = (const float4*)cent;

    float z0[NCLS], z1[NCLS], z2[NCLS], z3[NCLS];
    #pragma unroll
    for (int c = 0; c < NCLS; ++c) { z0[c]=0.f; z1[c]=0.f; z2[c]=0.f; z3[c]=0.f; }

    #pragma unroll 2
    for (int q = 0; q < 16; ++q) {
        const int o = sub + 4 * q;                  // lane's float4 slot in the row
        const float4 f0 = r0[o];                    // unconditional loads
        const float4 f1 = r1[o];
        const float4 f2 = r2[o];
        const float4 f3 = r3[o];
        #pragma unroll
        for (int c = 0; c < NCLS; ++c) {
            const float4 cc = cv[c * 64 + o];       // 16-way broadcast across groups
            z0[c] += f0.x*cc.x + f0.y*cc.y + f0.z*cc.z + f0.w*cc.w;
            z1[c] += f1.x*cc.x + f1.y*cc.y + f1.z*cc.z + f1.w*cc.w;
            z2[c] += f2.x*cc.x + f2.y*cc.y + f2.z*cc.z + f2.w*cc.w;
            z3[c] += f3.x*cc.x + f3.y*cc.y + f3.z*cc.z + f3.w*cc.w;
        }
    }

    // fused transpose-reduce across the 4-lane group: 3 shuffles per class,
    // lane sub ends holding the full logit vector for its own pixel
    const bool s1b = (sub & 1) != 0;
    const bool s2b = (sub & 2) != 0;
    float zm[NCLS];
    #pragma unroll
    for (int c = 0; c < NCLS; ++c) {
        float a  = s1b ? z1[c] : z0[c];
        float b  = s1b ? z0[c] : z1[c];
        a += __shfl_xor(b, 1);
        float a2 = s1b ? z3[c] : z2[c];
        float b2 = s1b ? z2[c] : z3[c];
        a2 += __shfl_xor(b2, 1);
        float k  = s2b ? a2 : a;
        float s  = s2b ? a  : a2;
        zm[c] = k + __shfl_xor(s, 2);
    }

    // masked log-softmax entropy for this lane's own pixel
    const float wme = s1b ? (s2b ? w3 : w1) : (s2b ? w2 : w0);
    float m = -3.4e38f;
    #pragma unroll
    for (int c = 0; c < NCLS; ++c)
        if ((seenM >> c) & 1) m = fmaxf(m, zm[c]);
    float ssum = 0.f, t1 = 0.f;
    #pragma unroll
    for (int c = 0; c < NCLS; ++c)
        if ((seenM >> c) & 1) {
            const float e = __expf(zm[c] - m);
            ssum += e; t1 += e * (zm[c] - m);
        }
    const float ent = t1 / ssum - __logf(ssum);
    float acc = (wme != 0.f) ? wme * ent : 0.f;

    // wave + block reduction of weighted entropy sum
    acc += __shfl_xor(acc, 32); acc += __shfl_xor(acc, 16);
    acc += __shfl_xor(acc, 8);  acc += __shfl_xor(acc, 4);
    acc += __shfl_xor(acc, 2);  acc += __shfl_xor(acc, 1);
    if (lane == 0) wacc[wv] = acc;
    __syncthreads();
    if (t == 0)
        unsafeAtomicAdd(&ws[OFF_TOT + (blockIdx.x & (REPL - 1))],
                        wacc[0] + wacc[1] + wacc[2] + wacc[3]);
}

// -------------------- finalize loss --------------------
__global__ void k_loss(const float* __restrict__ ws, float* __restrict__ out)
{
    if (threadIdx.x == 0 && blockIdx.x == 0) {
        float tot = 0.f, wsum = 0.f;
        for (int r = 0; r < REPL; ++r) { tot += ws[OFF_TOT + r]; wsum += ws[OFF_WSUM + r]; }
        out[NCLS * DF] = -tot / (wsum + (float)NPIX);
    }
}

extern "C" void kernel_launch(void* const* d_in, const int* in_sizes, int n_in,
                              void* d_out, int out_size, void* d_ws, size_t ws_size,
                              hipStream_t stream)
{
    const float* sfeat = (const float*)d_in[0];
    const float* tfeat = (const float*)d_in[1];
    const float* conf  = (const float*)d_in[2];
    const int*   sarg  = (const int*)d_in[3];
    const int*   targ  = (const int*)d_in[4];
    const int*   smask = (const int*)d_in[5];
    float* out = (float*)d_out;
    float* ws  = (float*)d_ws;

    hipMemsetAsync(d_ws, 0, MEMSET_BYTES, stream);
    k_phase1   <<<2048, 256, 0, stream>>>(sfeat, tfeat, conf, sarg, targ, smask, ws);
    k_centroids<<<NCLS, 256, 0, stream>>>(ws, out);
    k_entropy  <<<2048, 256, 0, stream>>>(sfeat, tfeat, conf, smask, ws);
    k_loss     <<<1,    64,  0, stream>>>(ws, out);
}